// Round 1
// baseline (689.658 us; speedup 1.0000x reference)
//
#include <hip/hip_runtime.h>

#define FDIM 64
#define GSEG 4096
#define LDS_LD 68   // 64 + 4 pad floats per LDS row -> conflict-free-ish

typedef __attribute__((ext_vector_type(8))) _Float16 half8;
typedef __attribute__((ext_vector_type(4))) float f32x4;

// ---------------- segment offsets (idx is sorted) ----------------
// offs[p][g] = index of first node with idx >= g; offs[p][G] = N.
__global__ __launch_bounds__(256) void seg_offsets_kernel(
    const int* __restrict__ iu, const int* __restrict__ iv, const int* __restrict__ iy,
    int* __restrict__ offs, int n)
{
    const int plane = blockIdx.y;
    const int* idx = plane == 0 ? iu : (plane == 1 ? iv : iy);
    int* o = offs + plane * (GSEG + 1);
    int i = blockIdx.x * 256 + threadIdx.x;
    if (i >= n) return;
    int cur = idx[i];
    int prev = (i == 0) ? -1 : idx[i - 1];
    for (int g = prev + 1; g <= cur; ++g) o[g] = i;
    if (i == n - 1) {
        for (int g = cur + 1; g <= GSEG; ++g) o[g] = n;
    }
}

// ---------------- fused gate-matmul + segment softmax + weighted pool ----------------
// One wave per (plane, segment). gate = sigmoid(x W^T + b) in (0,1) so
// exp(gate) needs no max-subtraction: softmax == exp(gate)/sum(exp(gate)).
// Per 16-node tile: x loaded in MFMA A-layout, z = x*W^T via 16x16x32 f16 MFMA
// (4 feature tiles x 2 K-steps), then e=exp(sigmoid(z)) and e, e*x accumulated.
__global__ __launch_bounds__(256) void pool_kernel(
    const float* __restrict__ xu, const float* __restrict__ xv, const float* __restrict__ xy,
    const float* __restrict__ Wu, const float* __restrict__ Wv, const float* __restrict__ Wy,
    const float* __restrict__ bu, const float* __restrict__ bv, const float* __restrict__ by,
    const int* __restrict__ offs, float* __restrict__ h)
{
    const int plane = blockIdx.y;
    const int wave = threadIdx.x >> 6;
    const int lane = threadIdx.x & 63;
    const int m = lane & 15;        // A-row / C-col / B-col within tile
    const int quad = lane >> 4;
    const int g = blockIdx.x * 4 + wave;

    const float* x = plane == 0 ? xu : (plane == 1 ? xv : xy);
    const float* W = plane == 0 ? Wu : (plane == 1 ? Wv : Wy);
    const float* b = plane == 0 ? bu : (plane == 1 ? bv : by);
    const int* og = offs + plane * (GSEG + 1);
    const int start = og[g];
    const int end = og[g + 1];

    __shared__ float xs[4][16 * LDS_LD];
    float* xw = xs[wave];

    // B fragments: z[i,f] = sum_k x[i,k] W[f,k]  => B[k][n] = W[n][k].
    // B-frag lane layout: n = lane&15, k = quad*8 + j (+32 per K-step).
    half8 bfr[4][2];
#pragma unroll
    for (int t = 0; t < 4; ++t) {
#pragma unroll
        for (int ks = 0; ks < 2; ++ks) {
            const float* wp = W + (t * 16 + m) * FDIM + ks * 32 + quad * 8;
            f32x4 w0 = *(const f32x4*)(wp);
            f32x4 w1 = *(const f32x4*)(wp + 4);
            half8 fr;
#pragma unroll
            for (int j = 0; j < 4; ++j) { fr[j] = (_Float16)w0[j]; fr[4 + j] = (_Float16)w1[j]; }
            bfr[t][ks] = fr;
        }
    }
    float bias[4];
#pragma unroll
    for (int t = 0; t < 4; ++t) bias[t] = b[t * 16 + m];

    float s_acc[4] = {0.f, 0.f, 0.f, 0.f};
    float o_acc[4] = {0.f, 0.f, 0.f, 0.f};

    for (int i0 = start; i0 < end; i0 += 16) {
        // A-layout load: lane covers node i0 + m, k = quad*8+j (+32)
        int ia = i0 + m;
        if (ia >= end) ia = end - 1;   // clamp: stays in-bounds, masked below
        const float* xr = x + (size_t)ia * FDIM;
        f32x4 a0 = *(const f32x4*)(xr + quad * 8);
        f32x4 a1 = *(const f32x4*)(xr + quad * 8 + 4);
        f32x4 a2 = *(const f32x4*)(xr + 32 + quad * 8);
        f32x4 a3 = *(const f32x4*)(xr + 32 + quad * 8 + 4);

        // stage fp32 tile to LDS for the C-layout elementwise read
        float* dst = xw + m * LDS_LD + quad * 8;
        *(f32x4*)(dst) = a0;
        *(f32x4*)(dst + 4) = a1;
        *(f32x4*)(dst + 32) = a2;
        *(f32x4*)(dst + 36) = a3;

        half8 af0, af1;
#pragma unroll
        for (int j = 0; j < 4; ++j) {
            af0[j] = (_Float16)a0[j]; af0[4 + j] = (_Float16)a1[j];
            af1[j] = (_Float16)a2[j]; af1[4 + j] = (_Float16)a3[j];
        }

        f32x4 c[4];
#pragma unroll
        for (int t = 0; t < 4; ++t) {
            f32x4 z4 = {0.f, 0.f, 0.f, 0.f};
            z4 = __builtin_amdgcn_mfma_f32_16x16x32_f16(af0, bfr[t][0], z4, 0, 0, 0);
            c[t] = __builtin_amdgcn_mfma_f32_16x16x32_f16(af1, bfr[t][1], z4, 0, 0, 0);
        }

        // order the LDS writes before the cross-lane reads (wave-private LDS,
        // HW DS queue is in-order per wave; fence blocks compiler reordering)
        __builtin_amdgcn_fence(__ATOMIC_ACQ_REL, "wavefront");

        // C/D layout: col = lane&15 (= m), row = quad*4 + reg
#pragma unroll
        for (int t = 0; t < 4; ++t) {
#pragma unroll
            for (int r = 0; r < 4; ++r) {
                const int row = quad * 4 + r;
                float z = c[t][r] + bias[t];
                float sg = __builtin_amdgcn_rcpf(1.0f + __expf(-z));
                float e = (i0 + row < end) ? __expf(sg) : 0.0f;
                float xval = xw[row * LDS_LD + t * 16 + m];
                s_acc[t] += e;
                o_acc[t] += e * xval;
            }
        }
        __builtin_amdgcn_fence(__ATOMIC_ACQ_REL, "wavefront"); // reads done before next overwrite
    }

    // reduce partials across the 4 quads (lanes ^16, ^32)
#pragma unroll
    for (int t = 0; t < 4; ++t) {
        float s = s_acc[t], ov = o_acc[t];
        s += __shfl_xor(s, 16); s += __shfl_xor(s, 32);
        ov += __shfl_xor(ov, 16); ov += __shfl_xor(ov, 32);
        if (quad == 0) {
            float r = (end > start) ? ov * __builtin_amdgcn_rcpf(s) : 0.0f;
            h[(size_t)g * 192 + plane * 64 + t * 16 + m] = r;
        }
    }
}

// ---------------- out = h @ Wo^T + bo  ([4096,192] x [256,192]^T) ----------------
// Block: 16 g x 256 o. Thread: 4 o x 4 g register tile. W and h chunks staged
// transposed in LDS so the inner loop is 2x b128 LDS reads + 16 FMA per k.
__global__ __launch_bounds__(256) void out_gemm_kernel(
    const float* __restrict__ h, const float* __restrict__ Wo,
    const float* __restrict__ bo, float* __restrict__ out)
{
    __shared__ float Ws[32 * 256];   // [k][o]
    __shared__ float Hs[32 * 20];    // [k][g(16)+pad]
    const int tid = threadIdx.x;
    const int to = tid & 63;         // o block: to*4 .. to*4+3
    const int tg = tid >> 6;         // g block: tg*4 .. tg*4+3
    const int g0 = blockIdx.x * 16;

    f32x4 acc[4];
    f32x4 bv = *(const f32x4*)(bo + to * 4);
#pragma unroll
    for (int j = 0; j < 4; ++j) acc[j] = bv;

    for (int kc = 0; kc < 6; ++kc) {
        const float* wsrc = Wo + (size_t)tid * 192 + kc * 32;
#pragma unroll
        for (int k4 = 0; k4 < 8; ++k4) {
            f32x4 w = *(const f32x4*)(wsrc + k4 * 4);
#pragma unroll
            for (int j = 0; j < 4; ++j) Ws[(k4 * 4 + j) * 256 + tid] = w[j];
        }
        {
            const int gg = tid >> 4;
            const int kk = (tid & 15) * 2;
            float2 v = *(const float2*)(h + (size_t)(g0 + gg) * 192 + kc * 32 + kk);
            Hs[kk * 20 + gg] = v.x;
            Hs[(kk + 1) * 20 + gg] = v.y;
        }
        __syncthreads();
#pragma unroll
        for (int k = 0; k < 32; ++k) {
            f32x4 wv = *(const f32x4*)(&Ws[k * 256 + to * 4]);
            f32x4 hv = *(const f32x4*)(&Hs[k * 20 + tg * 4]);
#pragma unroll
            for (int j = 0; j < 4; ++j) acc[j] += wv * hv[j];
        }
        __syncthreads();
    }
#pragma unroll
    for (int j = 0; j < 4; ++j) {
        *(f32x4*)(out + (size_t)(g0 + tg * 4 + j) * 256 + to * 4) = acc[j];
    }
}

extern "C" void kernel_launch(void* const* d_in, const int* in_sizes, int n_in,
                              void* d_out, int out_size, void* d_ws, size_t ws_size,
                              hipStream_t stream)
{
    // setup_inputs() dict order:
    // 0:x_u 1:Wg_u 2:bg_u 3:idx_u 4:x_v 5:Wg_v 6:bg_v 7:idx_v
    // 8:x_y 9:Wg_y 10:bg_y 11:idx_y 12:W_out 13:b_out 14:n_graphs
    const float* xu = (const float*)d_in[0];
    const float* Wu = (const float*)d_in[1];
    const float* bu = (const float*)d_in[2];
    const int*   iu = (const int*)d_in[3];
    const float* xv = (const float*)d_in[4];
    const float* Wv = (const float*)d_in[5];
    const float* bv = (const float*)d_in[6];
    const int*   iv = (const int*)d_in[7];
    const float* xy = (const float*)d_in[8];
    const float* Wy = (const float*)d_in[9];
    const float* by = (const float*)d_in[10];
    const int*   iy = (const int*)d_in[11];
    const float* Wo = (const float*)d_in[12];
    const float* bo = (const float*)d_in[13];

    const int N = in_sizes[0] / FDIM;

    int* offs = (int*)d_ws;                            // 3 * (G+1) ints
    float* h = (float*)((char*)d_ws + 65536);          // [G][192] fp32

    dim3 grid1((N + 255) / 256, 3);
    seg_offsets_kernel<<<grid1, 256, 0, stream>>>(iu, iv, iy, offs, N);

    dim3 grid2(GSEG / 4, 3);
    pool_kernel<<<grid2, 256, 0, stream>>>(xu, xv, xy, Wu, Wv, Wy, bu, bv, by, offs, h);

    out_gemm_kernel<<<GSEG / 16, 256, 0, stream>>>(h, Wo, bo, (float*)d_out);
}